// Round 4
// baseline (3135.125 us; speedup 1.0000x reference)
//
#include <hip/hip_runtime.h>

typedef short short8 __attribute__((ext_vector_type(8)));
typedef float floatx4 __attribute__((ext_vector_type(4)));

constexpr int N_PIX  = 16384;           // 4*64*64 pixels
constexpr int FEAT_N = N_PIX * 256;     // floats per feat buffer
constexpr int OFF_N  = N_PIX * 18;
constexpr int KDIM   = 2304;
constexpr int WB_L   = 2304 * 256;      // bf16 elems per deform layer
constexpr int WTO_L  = KDIM * 18;       // fp32 elems per offset layer

__device__ __forceinline__ unsigned short bf16_rn(float v) {
  unsigned u = __float_as_uint(v);
  return (unsigned short)((u + 0x7FFFu + ((u >> 16) & 1u)) >> 16);
}
__device__ __forceinline__ void split_bf16(float v, short& h, short& l) {
  unsigned short hu = bf16_rn(v);
  float hf = __uint_as_float(((unsigned)hu) << 16);
  h = (short)hu;
  l = (short)bf16_rn(v - hf);
}
__device__ __forceinline__ float tf16(short s) {
  return __uint_as_float(((unsigned)(unsigned short)s) << 16);
}

// ---------------- concat [x;y] NCHW -> feat NHWC (fp32) ----------------
__global__ __launch_bounds__(256) void concat_nhwc(const float* __restrict__ x,
                                                   const float* __restrict__ y,
                                                   float* __restrict__ feat) {
  __shared__ float tile[64][65];
  int bid = blockIdx.x;                 // b*256 + h*4 + ct
  int ct = bid & 3, h = (bid >> 2) & 63, b = bid >> 8;
  int c0 = ct * 64;
  const float* src = (c0 < 128) ? x : y;
  int cs = c0 & 127;
  int t = threadIdx.x;
  int w = t & 63, cl = t >> 6;
#pragma unroll
  for (int i = 0; i < 16; ++i) {
    int c = cl + i * 4;
    tile[c][w] = src[((b * 128 + cs + c) * 64 + h) * 64 + w];
  }
  __syncthreads();
  int c2 = t & 63, wl = t >> 6;
#pragma unroll
  for (int i = 0; i < 16; ++i) {
    int w2 = wl + i * 4;
    feat[((b * 64 + h) * 64 + w2) * 256 + c0 + c2] = tile[c2][w2];
  }
}

// ------------- weight prep: deform_w -> MFMA-fragment-linear hi/lo bf16 -------------
// flat short idx (per layer): ((kc*16 + nt)*64 + lane)*8 + j
//   k = kc*32 + (lane>>4)*8 + j ; o = nt*16 + (lane&15) ; ci = k&255 ; tap = k>>8
__global__ __launch_bounds__(256) void prep_wb(const float* __restrict__ dw,
                                               unsigned short* __restrict__ wbh,
                                               unsigned short* __restrict__ wbl) {
  int g = blockIdx.x * 256 + threadIdx.x;      // < 3*WB_L
  int l = g / WB_L, r = g % WB_L;
  int j = r & 7, lane = (r >> 3) & 63, nt = (r >> 9) & 15, kc = r >> 13;
  int k = kc * 32 + (lane >> 4) * 8 + j;
  int o = nt * 16 + (lane & 15);
  float w = dw[((l * 256 + o) * 256 + (k & 255)) * 9 + (k >> 8)];
  short h, lo; split_bf16(w, h, lo);
  wbh[g] = (unsigned short)h; wbl[g] = (unsigned short)lo;
}

// offset_w [4][18(o)][256(i)][3][3] -> wto[l][(tap*256+i)*18 + o]  (fp32, round-1)
__global__ __launch_bounds__(256) void t_ow(const float* __restrict__ ow,
                                            float* __restrict__ wto) {
  int g = blockIdx.x * 256 + threadIdx.x;      // < 4*41472
  int l = g / WTO_L, r = g % WTO_L;
  int o = r % 18, k = r / 18;
  int i = k & 255, tap = k >> 8;
  wto[g] = ow[(l * 18 + o) * KDIM + i * 9 + tap];
}

// ---------------- offset conv (3x3 SAME, 256 -> 18) — round-1 fp32, verified ----------------
template <bool NCHW>
__global__ __launch_bounds__(256) void off_conv(const float* __restrict__ feat,
                                                const float* __restrict__ wo,
                                                float* __restrict__ out) {
  __shared__ float red[256][19];
  int t = threadIdx.x;
  int lane = t & 63;
  int kq = __builtin_amdgcn_readfirstlane(t >> 6);   // wave-uniform K quarter
  int p = blockIdx.x * 64 + lane;
  int b = p >> 12, h = (p >> 6) & 63, w = p & 63;
  float acc[18] = {};
  for (int kc = kq * 36; kc < kq * 36 + 36; ++kc) {
    int k0 = kc * 16;
    int tap = k0 >> 8, c0 = k0 & 255;
    int y = h + tap / 3 - 1, xx = w + tap % 3 - 1;
    float a[16];
#pragma unroll
    for (int q = 0; q < 16; ++q) a[q] = 0.f;
    if ((unsigned)y < 64u && (unsigned)xx < 64u) {
      const float4* srcp =
          (const float4*)(feat + ((b * 64 + y) * 64 + xx) * 256 + c0);
#pragma unroll
      for (int q = 0; q < 4; ++q) {
        float4 v = srcp[q];
        a[q * 4 + 0] = v.x; a[q * 4 + 1] = v.y;
        a[q * 4 + 2] = v.z; a[q * 4 + 3] = v.w;
      }
    }
    const float* wp = wo + k0 * 18;   // wave-uniform -> scalar loads
#pragma unroll
    for (int kk = 0; kk < 16; ++kk)
#pragma unroll
      for (int o = 0; o < 18; ++o)
        acc[o] += a[kk] * wp[kk * 18 + o];
  }
#pragma unroll
  for (int o = 0; o < 18; ++o) red[t][o] = acc[o];
  __syncthreads();
  if (kq == 0) {
#pragma unroll
    for (int o = 0; o < 18; ++o) {
      float s = red[lane][o] + red[lane + 64][o] + red[lane + 128][o] +
                red[lane + 192][o];
      if (NCHW)
        out[(b * 18 + o) * 4096 + (p & 4095)] = s;
      else
        out[p * 18 + o] = s;
    }
  }
}

// ---------------- deform conv: staging byte-identical to round 2/3, but the
// MFMA triple is replaced by an in-thread EMULATION of the documented MFMA
// semantics computed from the staged Ah/Al (LDS) and BH/BL (global) bytes.
// Decode formulas are the exact inverse of the staging encode formulas.
__global__ __launch_bounds__(256) void deform_emu(
    const float* __restrict__ feat, const float* __restrict__ off,
    const unsigned short* __restrict__ wbh, const unsigned short* __restrict__ wbl,
    float* __restrict__ out) {
  __shared__ __align__(16) unsigned short Ah[64 * 32], Al[64 * 32];
  __shared__ float cy[9][64], cx[9][64];
  const int t = threadIdx.x;
  const int pbase = blockIdx.x * 64;
  const int bimg = pbase >> 12, h = (pbase >> 6) & 63;
  const float* fbase = feat + bimg * (4096 * 256);

  {  // sampling coords per (tap, pixel)
    int m = t & 63, p = pbase + m;
    for (int tap = t >> 6; tap < 9; tap += 4) {
      cy[tap][m] = off[p * 18 + 2 * tap]     + (float)(tap / 3 - 1 + h);
      cx[tap][m] = off[p * 18 + 2 * tap + 1] + (float)(tap % 3 - 1 + m);
    }
  }
  __syncthreads();

  const int m  = t & 63;                       // gather pixel
  const int cg = t >> 6;                       // gather channel-group (8 ch)
  const int lane = t & 63;
  const int wv = __builtin_amdgcn_readfirstlane(t >> 6);
  const int awoff = ((m >> 4) * 64 + cg * 16 + (m & 15)) * 8;  // frag-linear A slot
  const int col = lane & 15, r0 = (lane >> 4) * 4;

  floatx4 acc[4][4];
  const floatx4 z4 = {0.f, 0.f, 0.f, 0.f};
#pragma unroll
  for (int i = 0; i < 4; ++i)
#pragma unroll
    for (int jn = 0; jn < 4; ++jn) acc[i][jn] = z4;

  const short8* BH = (const short8*)wbh;
  const short8* BL = (const short8*)wbl;

  float4 pf[8];
  float w4[4];
  auto issue = [&](int kc) {
    int tap = kc >> 3, c0 = (kc & 7) * 32 + cg * 8;
    float py = cy[tap][m], px = cx[tap][m];
    float fy = floorf(py), fx = floorf(px);
    int iy = (int)fy, ix = (int)fx;
    float wy1 = py - fy, wx1 = px - fx;
    float wy0 = 1.f - wy1, wx0 = 1.f - wx1;
    w4[0] = wy0 * wx0; w4[1] = wy0 * wx1; w4[2] = wy1 * wx0; w4[3] = wy1 * wx1;
#pragma unroll
    for (int c = 0; c < 4; ++c) {
      int yy = iy + (c >> 1), xx = ix + (c & 1);
      bool ok = ((unsigned)yy < 64u) && ((unsigned)xx < 64u);
      if (!ok) w4[c] = 0.f;
      int yc = min(max(yy, 0), 63), xc = min(max(xx, 0), 63);
      const float4* p = (const float4*)(fbase + (yc * 64 + xc) * 256 + c0);
      pf[c * 2]     = p[0];
      pf[c * 2 + 1] = p[1];
    }
  };

  issue(0);
  for (int kc = 0; kc < 72; ++kc) {
    const float* pfp = (const float*)pf;
    short8 hv, lv;
#pragma unroll
    for (int j = 0; j < 8; ++j) {
      float v = w4[0] * pfp[j] + w4[1] * pfp[8 + j] + w4[2] * pfp[16 + j] +
                w4[3] * pfp[24 + j];
      short hh, ll; split_bf16(v, hh, ll);
      hv[j] = hh; lv[j] = ll;
    }
    __syncthreads();                 // prior chunk's frag reads complete
    *(short8*)&Ah[awoff] = hv;
    *(short8*)&Al[awoff] = lv;
    __syncthreads();

    if (kc + 1 < 72) issue(kc + 1);  // prefetch (keeps structure identical)

    // ---- EMULATED MFMA: slot (quad kq2, elem j) of lane L holds
    //      A[m = mi*16 + (L&15)][k = kq2*8+j],  B[k][n = nt*16 + (L&15)] ----
#pragma unroll
    for (int kq2 = 0; kq2 < 4; ++kq2) {
      float bf[4][8];
#pragma unroll
      for (int ni = 0; ni < 4; ++ni) {
        int sidx = (kc * 16 + wv * 4 + ni) * 64 + kq2 * 16 + col;
        short8 b8h = BH[sidx], b8l = BL[sidx];
#pragma unroll
        for (int j = 0; j < 8; ++j) bf[ni][j] = tf16(b8h[j]) + tf16(b8l[j]);
      }
#pragma unroll
      for (int mi = 0; mi < 4; ++mi)
#pragma unroll
        for (int r = 0; r < 4; ++r) {
          const short8 a8h = *(const short8*)&Ah[(mi * 64 + kq2 * 16 + r0 + r) * 8];
          const short8 a8l = *(const short8*)&Al[(mi * 64 + kq2 * 16 + r0 + r) * 8];
#pragma unroll
          for (int j = 0; j < 8; ++j) {
            float a = tf16(a8h[j]) + tf16(a8l[j]);
#pragma unroll
            for (int ni = 0; ni < 4; ++ni)
              acc[mi][ni][r] += a * bf[ni][j];
          }
        }
    }
  }

  // epilogue: C/D layout col=lane&15, row=(lane>>4)*4+reg  -> NHWC fp32
#pragma unroll
  for (int mi = 0; mi < 4; ++mi)
#pragma unroll
    for (int ni = 0; ni < 4; ++ni)
#pragma unroll
      for (int r = 0; r < 4; ++r) {
        int pg = pbase + mi * 16 + r0 + r;
        out[pg * 256 + wv * 64 + ni * 16 + col] = acc[mi][ni][r];
      }
}

// ---------------- launcher ----------------
extern "C" void kernel_launch(void* const* d_in, const int* in_sizes, int n_in,
                              void* d_out, int out_size, void* d_ws, size_t ws_size,
                              hipStream_t stream) {
  const float* x  = (const float*)d_in[0];
  const float* y  = (const float*)d_in[1];
  const float* ow = (const float*)d_in[2];   // [4][18][256][3][3]
  const float* dw = (const float*)d_in[3];   // [3][256][256][3][3]
  float* out = (float*)d_out;

  float* fA      = (float*)d_ws;
  float* fB      = fA + FEAT_N;
  float* off_buf = fB + FEAT_N;
  float* wto     = off_buf + OFF_N;          // 4 * WTO_L fp32
  unsigned short* wbh = (unsigned short*)(wto + 4 * WTO_L);
  unsigned short* wbl = wbh + 3 * WB_L;      // ~40.5 MB total

  concat_nhwc<<<dim3(1024), dim3(256), 0, stream>>>(x, y, fA);
  prep_wb<<<dim3(3 * WB_L / 256), dim3(256), 0, stream>>>(dw, wbh, wbl);
  t_ow<<<dim3(4 * WTO_L / 256), dim3(256), 0, stream>>>(ow, wto);

  float* cur = fA;
  float* nxt = fB;
  for (int i = 0; i < 3; ++i) {
    off_conv<false><<<dim3(256), dim3(256), 0, stream>>>(cur, wto + i * WTO_L,
                                                         off_buf);
    deform_emu<<<dim3(256), dim3(256), 0, stream>>>(
        cur, off_buf, wbh + i * WB_L, wbl + i * WB_L, nxt);
    float* tmp = cur; cur = nxt; nxt = tmp;
  }
  off_conv<true><<<dim3(256), dim3(256), 0, stream>>>(cur, wto + 3 * WTO_L, out);
}

// Round 5
// 797.391 us; speedup vs baseline: 3.9317x; 3.9317x over previous
//
#include <hip/hip_runtime.h>

typedef short short8 __attribute__((ext_vector_type(8)));
typedef float floatx4 __attribute__((ext_vector_type(4)));

constexpr int N_PIX  = 16384;           // 4*64*64 pixels
constexpr int FEAT_N = N_PIX * 256;     // floats per feat buffer
constexpr int OFF_N  = N_PIX * 18;
constexpr int KDIM   = 2304;
constexpr int WB_L   = 2304 * 256;      // bf16 elems per deform layer
constexpr int WTO_L  = KDIM * 18;       // fp32 elems per offset layer

__device__ __forceinline__ unsigned short bf16_rn(float v) {
  unsigned u = __float_as_uint(v);
  return (unsigned short)((u + 0x7FFFu + ((u >> 16) & 1u)) >> 16);
}
__device__ __forceinline__ void split_bf16(float v, short& h, short& l) {
  unsigned short hu = bf16_rn(v);
  float hf = __uint_as_float(((unsigned)hu) << 16);
  h = (short)hu;
  l = (short)bf16_rn(v - hf);
}

// ---------------- concat [x;y] NCHW -> feat NHWC (fp32) ----------------
__global__ __launch_bounds__(256) void concat_nhwc(const float* __restrict__ x,
                                                   const float* __restrict__ y,
                                                   float* __restrict__ feat) {
  __shared__ float tile[64][65];
  int bid = blockIdx.x;                 // b*256 + h*4 + ct
  int ct = bid & 3, h = (bid >> 2) & 63, b = bid >> 8;
  int c0 = ct * 64;
  const float* src = (c0 < 128) ? x : y;
  int cs = c0 & 127;
  int t = threadIdx.x;
  int w = t & 63, cl = t >> 6;
#pragma unroll
  for (int i = 0; i < 16; ++i) {
    int c = cl + i * 4;
    tile[c][w] = src[((b * 128 + cs + c) * 64 + h) * 64 + w];
  }
  __syncthreads();
  int c2 = t & 63, wl = t >> 6;
#pragma unroll
  for (int i = 0; i < 16; ++i) {
    int w2 = wl + i * 4;
    feat[((b * 64 + h) * 64 + w2) * 256 + c0 + c2] = tile[c2][w2];
  }
}

// ------------- weight prep: deform_w -> MFMA-fragment-linear hi/lo bf16 -------------
// flat short idx (per layer): ((kc*16 + nt)*64 + lane)*8 + j
//   k = kc*32 + (lane>>4)*8 + j ; o = nt*16 + (lane&15) ; ci = k&255 ; tap = k>>8
__global__ __launch_bounds__(256) void prep_wb(const float* __restrict__ dw,
                                               unsigned short* __restrict__ wbh,
                                               unsigned short* __restrict__ wbl) {
  int g = blockIdx.x * 256 + threadIdx.x;      // < 3*WB_L
  int l = g / WB_L, r = g % WB_L;
  int j = r & 7, lane = (r >> 3) & 63, nt = (r >> 9) & 15, kc = r >> 13;
  int k = kc * 32 + (lane >> 4) * 8 + j;
  int o = nt * 16 + (lane & 15);
  float w = dw[((l * 256 + o) * 256 + (k & 255)) * 9 + (k >> 8)];
  short h, lo; split_bf16(w, h, lo);
  wbh[g] = (unsigned short)h; wbl[g] = (unsigned short)lo;
}

// offset_w [4][18(o)][256(i)][3][3] -> wto[l][(tap*256+i)*18 + o]  (fp32, round-1)
__global__ __launch_bounds__(256) void t_ow(const float* __restrict__ ow,
                                            float* __restrict__ wto) {
  int g = blockIdx.x * 256 + threadIdx.x;      // < 4*41472
  int l = g / WTO_L, r = g % WTO_L;
  int o = r % 18, k = r / 18;
  int i = k & 255, tap = k >> 8;
  wto[g] = ow[(l * 18 + o) * KDIM + i * 9 + tap];
}

// ---------------- offset conv (3x3 SAME, 256 -> 18) — round-1 fp32, verified ----------------
template <bool NCHW>
__global__ __launch_bounds__(256) void off_conv(const float* __restrict__ feat,
                                                const float* __restrict__ wo,
                                                float* __restrict__ out) {
  __shared__ float red[256][19];
  int t = threadIdx.x;
  int lane = t & 63;
  int kq = __builtin_amdgcn_readfirstlane(t >> 6);   // wave-uniform K quarter
  int p = blockIdx.x * 64 + lane;
  int b = p >> 12, h = (p >> 6) & 63, w = p & 63;
  float acc[18] = {};
  for (int kc = kq * 36; kc < kq * 36 + 36; ++kc) {
    int k0 = kc * 16;
    int tap = k0 >> 8, c0 = k0 & 255;
    int y = h + tap / 3 - 1, xx = w + tap % 3 - 1;
    float a[16];
#pragma unroll
    for (int q = 0; q < 16; ++q) a[q] = 0.f;
    if ((unsigned)y < 64u && (unsigned)xx < 64u) {
      const float4* srcp =
          (const float4*)(feat + ((b * 64 + y) * 64 + xx) * 256 + c0);
#pragma unroll
      for (int q = 0; q < 4; ++q) {
        float4 v = srcp[q];
        a[q * 4 + 0] = v.x; a[q * 4 + 1] = v.y;
        a[q * 4 + 2] = v.z; a[q * 4 + 3] = v.w;
      }
    }
    const float* wp = wo + k0 * 18;   // wave-uniform -> scalar loads
#pragma unroll
    for (int kk = 0; kk < 16; ++kk)
#pragma unroll
      for (int o = 0; o < 18; ++o)
        acc[o] += a[kk] * wp[kk * 18 + o];
  }
#pragma unroll
  for (int o = 0; o < 18; ++o) red[t][o] = acc[o];
  __syncthreads();
  if (kq == 0) {
#pragma unroll
    for (int o = 0; o < 18; ++o) {
      float s = red[lane][o] + red[lane + 64][o] + red[lane + 128][o] +
                red[lane + 192][o];
      if (NCHW)
        out[(b * 18 + o) * 4096 + (p & 4095)] = s;
      else
        out[p * 18 + o] = s;
    }
  }
}

// ---------------- deform conv: gather + MFMA GEMM with SELF-CALIBRATED C/D map ----
// Staging byte-identical to the emulation-verified round-4 kernel. A calibration
// MFMA (A=I, B[k][n]=k*16+n, exact in bf16) measures the true per-lane/per-reg
// (row,col) of the D fragment; the epilogue uses the measured map. Correct under
// any bijective lane permutation in A/B/D and any shared K-slot permutation.
__global__ __launch_bounds__(256) void deform_mfma(
    const float* __restrict__ feat, const float* __restrict__ off,
    const unsigned short* __restrict__ wbh, const unsigned short* __restrict__ wbl,
    float* __restrict__ out) {
  __shared__ __align__(16) unsigned short Ah[64 * 32], Al[64 * 32];
  __shared__ float cy[9][64], cx[9][64];
  const int t = threadIdx.x;
  const int pbase = blockIdx.x * 64;
  const int bimg = pbase >> 12, h = (pbase >> 6) & 63;
  const float* fbase = feat + bimg * (4096 * 256);

  {  // sampling coords per (tap, pixel)
    int m = t & 63, p = pbase + m;
    for (int tap = t >> 6; tap < 9; tap += 4) {
      cy[tap][m] = off[p * 18 + 2 * tap]     + (float)(tap / 3 - 1 + h);
      cx[tap][m] = off[p * 18 + 2 * tap + 1] + (float)(tap % 3 - 1 + m);
    }
  }
  __syncthreads();

  const int m  = t & 63;                       // gather pixel
  const int cg = t >> 6;                       // gather channel-group (8 ch)
  const int lane = t & 63;
  const int wv = __builtin_amdgcn_readfirstlane(t >> 6);
  const int awoff = ((m >> 4) * 64 + cg * 16 + (m & 15)) * 8;  // frag-linear A slot

  floatx4 acc[4][4];
  const floatx4 z4 = {0.f, 0.f, 0.f, 0.f};
#pragma unroll
  for (int i = 0; i < 4; ++i)
#pragma unroll
    for (int jn = 0; jn < 4; ++jn) acc[i][jn] = z4;

  // ---- calibration MFMA: measure the true C/D slot map ----
  int rowmap[4], colmap[4];
  {
    short8 cA, cB;
    int own = lane & 15, q = (lane >> 4) & 3;
#pragma unroll
    for (int j = 0; j < 8; ++j) {
      int k = q * 8 + j;                     // assumed k-slot id (shared-perm safe)
      cA[j] = (short)((k == own) ? bf16_rn(1.0f) : 0);
      cB[j] = (short)((k < 16) ? bf16_rn((float)(k * 16 + own)) : 0);
    }
    floatx4 cal = __builtin_amdgcn_mfma_f32_16x16x32_bf16(cA, cB, z4, 0, 0, 0);
#pragma unroll
    for (int r = 0; r < 4; ++r) {
      int v = (int)(cal[r] + 0.5f);          // exact integer in [0,255]
      rowmap[r] = (v >> 4) & 15;
      colmap[r] = v & 15;
    }
  }

  const short8* BH = (const short8*)wbh;
  const short8* BL = (const short8*)wbl;

  float4 pf[8];
  float w4[4];
  auto issue = [&](int kc) {
    int tap = kc >> 3, c0 = (kc & 7) * 32 + cg * 8;
    float py = cy[tap][m], px = cx[tap][m];
    float fy = floorf(py), fx = floorf(px);
    int iy = (int)fy, ix = (int)fx;
    float wy1 = py - fy, wx1 = px - fx;
    float wy0 = 1.f - wy1, wx0 = 1.f - wx1;
    w4[0] = wy0 * wx0; w4[1] = wy0 * wx1; w4[2] = wy1 * wx0; w4[3] = wy1 * wx1;
#pragma unroll
    for (int c = 0; c < 4; ++c) {
      int yy = iy + (c >> 1), xx = ix + (c & 1);
      bool ok = ((unsigned)yy < 64u) && ((unsigned)xx < 64u);
      if (!ok) w4[c] = 0.f;
      int yc = min(max(yy, 0), 63), xc = min(max(xx, 0), 63);
      const float4* p = (const float4*)(fbase + (yc * 64 + xc) * 256 + c0);
      pf[c * 2]     = p[0];
      pf[c * 2 + 1] = p[1];
    }
  };

  issue(0);
  for (int kc = 0; kc < 72; ++kc) {
    const float* pfp = (const float*)pf;
    short8 hv, lv;
#pragma unroll
    for (int j = 0; j < 8; ++j) {
      float v = w4[0] * pfp[j] + w4[1] * pfp[8 + j] + w4[2] * pfp[16 + j] +
                w4[3] * pfp[24 + j];
      short hh, ll; split_bf16(v, hh, ll);
      hv[j] = hh; lv[j] = ll;
    }
    __syncthreads();                 // prior chunk's frag reads complete
    *(short8*)&Ah[awoff] = hv;
    *(short8*)&Al[awoff] = lv;
    __syncthreads();

    if (kc + 1 < 72) issue(kc + 1);  // prefetch under the MFMA phase

    short8 ah[4], al[4], bh[4], bl[4];
#pragma unroll
    for (int mi = 0; mi < 4; ++mi) {
      ah[mi] = *(const short8*)&Ah[(mi * 64 + lane) * 8];
      al[mi] = *(const short8*)&Al[(mi * 64 + lane) * 8];
    }
#pragma unroll
    for (int ni = 0; ni < 4; ++ni) {
      int bidx = (kc * 16 + wv * 4 + ni) * 64 + lane;
      bh[ni] = BH[bidx];
      bl[ni] = BL[bidx];
    }
#pragma unroll
    for (int mi = 0; mi < 4; ++mi)
#pragma unroll
      for (int ni = 0; ni < 4; ++ni) {
        acc[mi][ni] = __builtin_amdgcn_mfma_f32_16x16x32_bf16(ah[mi], bh[ni], acc[mi][ni], 0, 0, 0);
        acc[mi][ni] = __builtin_amdgcn_mfma_f32_16x16x32_bf16(ah[mi], bl[ni], acc[mi][ni], 0, 0, 0);
        acc[mi][ni] = __builtin_amdgcn_mfma_f32_16x16x32_bf16(al[mi], bh[ni], acc[mi][ni], 0, 0, 0);
      }
  }

  // epilogue: use the MEASURED C/D map -> NHWC fp32
#pragma unroll
  for (int mi = 0; mi < 4; ++mi)
#pragma unroll
    for (int ni = 0; ni < 4; ++ni)
#pragma unroll
      for (int r = 0; r < 4; ++r) {
        int pg = pbase + mi * 16 + rowmap[r];
        out[pg * 256 + wv * 64 + ni * 16 + colmap[r]] = acc[mi][ni][r];
      }
}

// ---------------- launcher ----------------
extern "C" void kernel_launch(void* const* d_in, const int* in_sizes, int n_in,
                              void* d_out, int out_size, void* d_ws, size_t ws_size,
                              hipStream_t stream) {
  const float* x  = (const float*)d_in[0];
  const float* y  = (const float*)d_in[1];
  const float* ow = (const float*)d_in[2];   // [4][18][256][3][3]
  const float* dw = (const float*)d_in[3];   // [3][256][256][3][3]
  float* out = (float*)d_out;

  float* fA      = (float*)d_ws;
  float* fB      = fA + FEAT_N;
  float* off_buf = fB + FEAT_N;
  float* wto     = off_buf + OFF_N;          // 4 * WTO_L fp32
  unsigned short* wbh = (unsigned short*)(wto + 4 * WTO_L);
  unsigned short* wbl = wbh + 3 * WB_L;      // ~40.5 MB total

  concat_nhwc<<<dim3(1024), dim3(256), 0, stream>>>(x, y, fA);
  prep_wb<<<dim3(3 * WB_L / 256), dim3(256), 0, stream>>>(dw, wbh, wbl);
  t_ow<<<dim3(4 * WTO_L / 256), dim3(256), 0, stream>>>(ow, wto);

  float* cur = fA;
  float* nxt = fB;
  for (int i = 0; i < 3; ++i) {
    off_conv<false><<<dim3(256), dim3(256), 0, stream>>>(cur, wto + i * WTO_L,
                                                         off_buf);
    deform_mfma<<<dim3(256), dim3(256), 0, stream>>>(
        cur, off_buf, wbh + i * WB_L, wbl + i * WB_L, nxt);
    float* tmp = cur; cur = nxt; nxt = tmp;
  }
  off_conv<true><<<dim3(256), dim3(256), 0, stream>>>(cur, wto + 3 * WTO_L, out);
}